// Round 1
// baseline (208.909 us; speedup 1.0000x reference)
//
#include <hip/hip_runtime.h>

#define N_E 512
#define DIM 64
#define HW  4096            // 64*64
#define NPTS (32 * HW)      // 131072 points
#define OUT_ELEMS (NPTS * DIM)  // 8388608

__global__ void vq_zero_loss(float* __restrict__ out) {
    out[0] = 0.0f;
}

__global__ __launch_bounds__(256) void vq_main(
    const float* __restrict__ z,    // [32, 64, 64, 64] NCHW
    const float* __restrict__ emb,  // [512, 64]
    float* __restrict__ out)        // [0] = loss, [1..] = z_q_st NCHW
{
    const int t  = threadIdx.x;
    const int p  = blockIdx.x * 256 + t;   // flat point index (b*4096 + hw)
    const int b  = p >> 12;
    const int hw = p & 4095;

    // ---- per-block e2 = ||emb_row||^2 into LDS (each thread does 2 rows) ----
    __shared__ float se2[N_E];
    {
        const float* r0 = emb + (2 * t) * DIM;
        float s0 = 0.0f, s1 = 0.0f;
#pragma unroll
        for (int k = 0; k < DIM; ++k) {
            float v0 = r0[k];       s0 = fmaf(v0, v0, s0);
            float v1 = r0[DIM + k]; s1 = fmaf(v1, v1, s1);
        }
        se2[2 * t]     = s0;
        se2[2 * t + 1] = s1;
    }

    // ---- load this point's z row into registers (coalesced per channel) ----
    const float* zb = z + (size_t)(b * DIM) * HW + hw;
    float zr[DIM];
    float z2 = 0.0f;
#pragma unroll
    for (int c = 0; c < DIM; ++c) {
        zr[c] = zb[(size_t)c * HW];
        z2 = fmaf(zr[c], zr[c], z2);
    }
    __syncthreads();

    // ---- argmin over 512 codebook rows; emb access is wave-uniform ----
    float dmin = 3.4e38f;
    int   imin = 0;
#pragma unroll 1
    for (int e = 0; e < N_E; e += 2) {
        const float* er = emb + e * DIM;
        float a0 = 0.0f, a1 = 0.0f, c0 = 0.0f, c1 = 0.0f;
#pragma unroll
        for (int k = 0; k < DIM; k += 2) {
            a0 = fmaf(zr[k],     er[k],           a0);
            a1 = fmaf(zr[k + 1], er[k + 1],       a1);
            c0 = fmaf(zr[k],     er[DIM + k],     c0);
            c1 = fmaf(zr[k + 1], er[DIM + k + 1], c1);
        }
        float d0 = fmaf(-2.0f, a0 + a1, z2 + se2[e]);
        float d1 = fmaf(-2.0f, c0 + c1, z2 + se2[e + 1]);
        if (d0 < dmin) { dmin = d0; imin = e; }
        if (d1 < dmin) { dmin = d1; imin = e + 1; }
    }

    // ---- epilogue: write z_q (coalesced) + accumulate loss using zr in regs ----
    const float* qrow = emb + imin * DIM;   // per-lane gather, L1/L2-hot
    float* op = out + 1 + (size_t)(b * DIM) * HW + hw;
    float acc = 0.0f;
#pragma unroll
    for (int c = 0; c < DIM; ++c) {
        float v = qrow[c];
        op[(size_t)c * HW] = v;
        float d = v - zr[c];
        acc = fmaf(d, d, acc);
    }

    // ---- block reduction of squared error, one atomic per block ----
#pragma unroll
    for (int o = 32; o > 0; o >>= 1) acc += __shfl_down(acc, o, 64);
    __shared__ float sred[4];
    if ((t & 63) == 0) sred[t >> 6] = acc;
    __syncthreads();
    if (t == 0) {
        float s = (sred[0] + sred[1]) + (sred[2] + sred[3]);
        atomicAdd(out, s * (1.25f / (float)OUT_ELEMS));
    }
}

extern "C" void kernel_launch(void* const* d_in, const int* in_sizes, int n_in,
                              void* d_out, int out_size, void* d_ws, size_t ws_size,
                              hipStream_t stream) {
    const float* z   = (const float*)d_in[0];
    const float* emb = (const float*)d_in[1];
    float* out = (float*)d_out;

    vq_zero_loss<<<1, 1, 0, stream>>>(out);
    vq_main<<<NPTS / 256, 256, 0, stream>>>(z, emb, out);
}